// Round 1
// baseline (2624.348 us; speedup 1.0000x reference)
//
#include <hip/hip_runtime.h>
#include <hip/hip_bf16.h>
#include <math.h>

#define T_    1024
#define HID_  2048
#define NH    16
#define NKV   4
#define DH    128
#define TOPK_ 256
#define HI_   4
#define DI_   32

#ifndef INFINITY
#define INFINITY (__builtin_inff())
#endif

// ---------------- tiled fp32 GEMM: C[M,N] = A[M,K] @ B[K,N] ----------------
__global__ void gemm_f32(const float* __restrict__ A, const float* __restrict__ B,
                         float* __restrict__ C, int M, int N, int K) {
    __shared__ float As[16][64 + 1];
    __shared__ float Bs[16][64 + 1];
    const int tid = threadIdx.x;
    const int tx = tid & 15, ty = tid >> 4;
    const int brow = blockIdx.y * 64, bcol = blockIdx.x * 64;

    float acc[4][4];
#pragma unroll
    for (int i = 0; i < 4; ++i)
#pragma unroll
        for (int j = 0; j < 4; ++j) acc[i][j] = 0.f;

    for (int k0 = 0; k0 < K; k0 += 16) {
        // load A tile (64 rows x 16 k), store transposed As[k][m]
#pragma unroll
        for (int it = 0; it < 4; ++it) {
            int i = tid + it * 256;            // 0..1023
            int r = i >> 4, c = i & 15;
            As[c][r] = A[(size_t)(brow + r) * K + (k0 + c)];
        }
        // load B tile (16 k x 64 cols)
#pragma unroll
        for (int it = 0; it < 4; ++it) {
            int i = tid + it * 256;
            int r = i >> 6, c = i & 63;
            int col = bcol + c;
            Bs[r][c] = (col < N) ? B[(size_t)(k0 + r) * N + col] : 0.f;
        }
        __syncthreads();
#pragma unroll
        for (int kk = 0; kk < 16; ++kk) {
            float a[4], b[4];
#pragma unroll
            for (int i = 0; i < 4; ++i) a[i] = As[kk][ty * 4 + i];
#pragma unroll
            for (int j = 0; j < 4; ++j) b[j] = Bs[kk][tx * 4 + j];
#pragma unroll
            for (int i = 0; i < 4; ++i)
#pragma unroll
                for (int j = 0; j < 4; ++j) acc[i][j] += a[i] * b[j];
        }
        __syncthreads();
    }
#pragma unroll
    for (int i = 0; i < 4; ++i) {
        int r = brow + ty * 4 + i;
#pragma unroll
        for (int j = 0; j < 4; ++j) {
            int c = bcol + tx * 4 + j;
            if (c < N) C[(size_t)r * N + c] = acc[i][j];
        }
    }
}

// ---------------- RoPE + RMSNorm over D=128 (one wave per (t,h)) ----------------
__global__ void rope_rms(float* __restrict__ x, const float* __restrict__ cosb,
                         const float* __restrict__ sinb, int Hn) {
    const int t = blockIdx.x, h = blockIdx.y, lane = threadIdx.x;  // block=64
    float* row = x + ((size_t)t * Hn + h) * DH;
    float a = row[lane];
    float b = row[lane + 64];
    float c0 = cosb[t * DH + lane],      s0 = sinb[t * DH + lane];
    float c1 = cosb[t * DH + lane + 64], s1 = sinb[t * DH + lane + 64];
    // rotate_half: first half gets -x2, second half gets x1
    float r0 = a * c0 - b * s0;
    float r1 = b * c1 + a * s1;
    float ss = r0 * r0 + r1 * r1;
#pragma unroll
    for (int o = 32; o > 0; o >>= 1) ss += __shfl_xor(ss, o);
    float inv = rsqrtf(ss * (1.0f / 128.0f) + 1.1920929e-07f);
    row[lane]      = r0 * inv;
    row[lane + 64] = r1 * inv;
}

// ---------------- lightning indexer scores: S[t][s] for s<=t ----------------
__global__ void indexer_kernel(const float* __restrict__ qi, const float* __restrict__ wi,
                               const float* __restrict__ ki, float* __restrict__ S) {
    const int t = blockIdx.x;  // block=256
    __shared__ float sq[HI_][DI_];
    __shared__ float sw[HI_];
    if (threadIdx.x < HI_ * DI_) sq[threadIdx.x / DI_][threadIdx.x % DI_] = qi[t * (HI_ * DI_) + threadIdx.x];
    if (threadIdx.x < HI_) sw[threadIdx.x] = wi[t * HI_ + threadIdx.x];
    __syncthreads();
    for (int s = threadIdx.x; s <= t; s += 256) {
        const float* kr = ki + s * DI_;
        float acc = 0.f;
#pragma unroll
        for (int j = 0; j < HI_; ++j) {
            float d = 0.f;
#pragma unroll
            for (int dd = 0; dd < DI_; ++dd) d += sq[j][dd] * kr[dd];
            acc += sw[j] * fmaxf(d, 0.f);
        }
        S[(size_t)t * T_ + s] = acc;
    }
}

// ---------------- exact top-256 per row (value desc, index asc) ----------------
__global__ void topk_kernel(const float* __restrict__ S, int* __restrict__ idxout,
                            int* __restrict__ cnt) {
    const int t = blockIdx.x;     // block=256
    const int tid = threadIdx.x;
    if (t < TOPK_) {
        idxout[(size_t)t * TOPK_ + tid] = tid;   // all valid s<=t are selected
        if (tid == 0) cnt[t] = t + 1;
        return;
    }
    const int n = t + 1;
    const float* Srow = S + (size_t)t * T_;
    float v0 = (tid       < n) ? Srow[tid]       : -INFINITY;
    float v1 = (tid + 256 < n) ? Srow[tid + 256] : -INFINITY;
    float v2 = (tid + 512 < n) ? Srow[tid + 512] : -INFINITY;
    float v3 = (tid + 768 < n) ? Srow[tid + 768] : -INFINITY;

    __shared__ float wv[4];
    __shared__ int   wsx[4];
    __shared__ int   ssel;
    const int lane = tid & 63, wave = tid >> 6;

    for (int k = 0; k < TOPK_; ++k) {
        // local argmax over own 4 slots (increasing s => ties keep earlier)
        float bv = v0; int bs = tid;
        if (v1 > bv) { bv = v1; bs = tid + 256; }
        if (v2 > bv) { bv = v2; bs = tid + 512; }
        if (v3 > bv) { bv = v3; bs = tid + 768; }
        // wave butterfly argmax with (value desc, index asc)
#pragma unroll
        for (int o = 32; o > 0; o >>= 1) {
            float ov = __shfl_xor(bv, o);
            int   os = __shfl_xor(bs, o);
            if (ov > bv || (ov == bv && os < bs)) { bv = ov; bs = os; }
        }
        if (lane == 0) { wv[wave] = bv; wsx[wave] = bs; }
        __syncthreads();
        if (tid == 0) {
            float fv = wv[0]; int fs = wsx[0];
#pragma unroll
            for (int w2 = 1; w2 < 4; ++w2)
                if (wv[w2] > fv || (wv[w2] == fv && wsx[w2] < fs)) { fv = wv[w2]; fs = wsx[w2]; }
            ssel = fs;
            idxout[(size_t)t * TOPK_ + k] = fs;
        }
        __syncthreads();
        int sel = ssel;
        if      (sel == tid)       v0 = -INFINITY;
        else if (sel == tid + 256) v1 = -INFINITY;
        else if (sel == tid + 512) v2 = -INFINITY;
        else if (sel == tid + 768) v3 = -INFINITY;
    }
    if (tid == 0) cnt[t] = TOPK_;
}

// ---------------- sparse GQA over selected tokens ----------------
// grid (T, NKV), block 256 = 4 waves; wave g handles query head h = n*4+g
__global__ void attn_kernel(const float* __restrict__ q, const float* __restrict__ k,
                            const float* __restrict__ v, const int* __restrict__ idx,
                            const int* __restrict__ cnt, float* __restrict__ attn) {
    const int t = blockIdx.x, n = blockIdx.y;
    const int tid = threadIdx.x;
    const int wave = tid >> 6, lane = tid & 63;
    const int h = n * 4 + wave;
    const int C = cnt[t];

    __shared__ float sp[4][TOPK_];
    __shared__ int   sidx[TOPK_];
    sidx[tid] = idx[(size_t)t * TOPK_ + tid];
    __syncthreads();

    const float* qr = q + (size_t)t * (NH * DH) + h * DH;
    const float scale = 0.08838834764831845f;  // 1/sqrt(128)

    float sc[4];
#pragma unroll
    for (int i = 0; i < 4; ++i) {
        int j = lane + 64 * i;
        float d = -INFINITY;
        if (j < C) {
            int s = sidx[j];
            const float* kr = k + (size_t)s * (NKV * DH) + n * DH;
            float acc = 0.f;
#pragma unroll
            for (int dd = 0; dd < DH; ++dd) acc += qr[dd] * kr[dd];
            d = acc * scale;
        }
        sc[i] = d;
    }
    // wave softmax over 256 slots
    float m = fmaxf(fmaxf(sc[0], sc[1]), fmaxf(sc[2], sc[3]));
#pragma unroll
    for (int o = 32; o > 0; o >>= 1) m = fmaxf(m, __shfl_xor(m, o));
    float sum = 0.f;
#pragma unroll
    for (int i = 0; i < 4; ++i) {
        float e = (sc[i] == -INFINITY) ? 0.f : expf(sc[i] - m);
        sp[wave][lane + 64 * i] = e;
        sum += e;
    }
#pragma unroll
    for (int o = 32; o > 0; o >>= 1) sum += __shfl_xor(sum, o);
    float inv = 1.f / sum;
    __syncthreads();

    // PV: lane owns dims lane and lane+64
    float o0 = 0.f, o1 = 0.f;
    for (int j = 0; j < C; ++j) {
        int s = sidx[j];
        const float* vr = v + (size_t)s * (NKV * DH) + n * DH;
        float p = sp[wave][j];
        o0 += p * vr[lane];
        o1 += p * vr[lane + 64];
    }
    attn[(size_t)t * (NH * DH) + h * DH + lane]      = o0 * inv;
    attn[(size_t)t * (NH * DH) + h * DH + lane + 64] = o1 * inv;
}

// ---------------- launch ----------------
extern "C" void kernel_launch(void* const* d_in, const int* in_sizes, int n_in,
                              void* d_out, int out_size, void* d_ws, size_t ws_size,
                              hipStream_t stream) {
    const float* x    = (const float*)d_in[0];
    const float* cosb = (const float*)d_in[1];
    const float* sinb = (const float*)d_in[2];
    const float* Wq   = (const float*)d_in[3];
    const float* Wk   = (const float*)d_in[4];
    const float* Wv   = (const float*)d_in[5];
    const float* Wo   = (const float*)d_in[6];
    const float* Wqi  = (const float*)d_in[7];
    const float* Wwi  = (const float*)d_in[8];
    const float* Wki  = (const float*)d_in[9];
    float* out = (float*)d_out;

    float* ws = (float*)d_ws;
    float* qb   = ws;                       // 1024*2048
    float* kb   = qb   + (size_t)T_ * NH * DH;     // 1024*512
    float* vb   = kb   + (size_t)T_ * NKV * DH;    // 1024*512
    float* qib  = vb   + (size_t)T_ * NKV * DH;    // 1024*128
    float* wib  = qib  + (size_t)T_ * HI_ * DI_;   // 1024*4
    float* kib  = wib  + (size_t)T_ * HI_;         // 1024*32
    float* Sb   = kib  + (size_t)T_ * DI_;         // 1024*1024
    float* attn = Sb   + (size_t)T_ * T_;          // 1024*2048
    int*   idxb = (int*)(attn + (size_t)T_ * NH * DH);  // 1024*256
    int*   cntb = idxb + (size_t)T_ * TOPK_;            // 1024

    dim3 blk(256);
    // projections
    gemm_f32<<<dim3(HID_ / 64, T_ / 64), blk, 0, stream>>>(x, Wq, qb, T_, NH * DH, HID_);
    gemm_f32<<<dim3((NKV * DH) / 64, T_ / 64), blk, 0, stream>>>(x, Wk, kb, T_, NKV * DH, HID_);
    gemm_f32<<<dim3((NKV * DH) / 64, T_ / 64), blk, 0, stream>>>(x, Wv, vb, T_, NKV * DH, HID_);
    gemm_f32<<<dim3((HI_ * DI_) / 64, T_ / 64), blk, 0, stream>>>(x, Wqi, qib, T_, HI_ * DI_, HID_);
    gemm_f32<<<dim3(1, T_ / 64), blk, 0, stream>>>(x, Wwi, wib, T_, HI_, HID_);
    gemm_f32<<<dim3(1, T_ / 64), blk, 0, stream>>>(x, Wki, kib, T_, DI_, HID_);

    // rope + rms on q,k
    rope_rms<<<dim3(T_, NH), dim3(64), 0, stream>>>(qb, cosb, sinb, NH);
    rope_rms<<<dim3(T_, NKV), dim3(64), 0, stream>>>(kb, cosb, sinb, NKV);

    // indexer scores + topk
    indexer_kernel<<<dim3(T_), blk, 0, stream>>>(qib, wib, kib, Sb);
    topk_kernel<<<dim3(T_), blk, 0, stream>>>(Sb, idxb, cntb);

    // sparse attention
    attn_kernel<<<dim3(T_, NKV), blk, 0, stream>>>(qb, kb, vb, idxb, cntb, attn);

    // output projection
    gemm_f32<<<dim3(HID_ / 64, T_ / 64), blk, 0, stream>>>(attn, Wo, out, T_, HID_, HID_);
}

// Round 2
// 788.904 us; speedup vs baseline: 3.3266x; 3.3266x over previous
//
#include <hip/hip_runtime.h>
#include <hip/hip_bf16.h>
#include <math.h>

#define T_    1024
#define HID_  2048
#define NH    16
#define NKV   4
#define DH    128
#define TOPK_ 256
#define HI_   4
#define DI_   32
#define NPROJ 3072          // q(2048) + k(512) + v(512)
#define NIDX  164           // qi(128) + wi(4) + ki(32)

#ifndef INFINITY
#define INFINITY (__builtin_inff())
#endif

typedef __attribute__((ext_vector_type(8))) short bf16x8;
typedef __attribute__((ext_vector_type(4))) float f32x4;

__device__ inline float bflo(unsigned int u) { return __uint_as_float(u << 16); }
__device__ inline float bfhi(unsigned int u) { return __uint_as_float(u & 0xffff0000u); }
__device__ inline unsigned int packbf(float f) {   // RNE f32->bf16 (bits in low 16)
    unsigned int u = __float_as_uint(f);
    return (u + 0x7fffu + ((u >> 16) & 1u)) >> 16;
}

// ---------------- cast x f32 -> bf16 (8 elems/thread) ----------------
__global__ __launch_bounds__(256) void cast_x(const float* __restrict__ in,
                                              unsigned short* __restrict__ outb, int n8) {
    int e = blockIdx.x * 256 + threadIdx.x;
    if (e >= n8) return;
    const float4* p = (const float4*)(in + (size_t)e * 8);
    float4 a = p[0], b = p[1];
    uint4 r;
    r.x = packbf(a.x) | (packbf(a.y) << 16);
    r.y = packbf(a.z) | (packbf(a.w) << 16);
    r.z = packbf(b.x) | (packbf(b.y) << 16);
    r.w = packbf(b.z) | (packbf(b.w) << 16);
    *(uint4*)(outb + (size_t)e * 8) = r;
}

// ---------------- transpose+cast W [K=2048][N] f32 -> Wt [N][2048] bf16 ----------------
__global__ void tcast(const float* __restrict__ W, unsigned short* __restrict__ Wt, int N) {
    __shared__ float tile[32][33];
    const int n0 = blockIdx.x * 32, k0 = blockIdx.y * 32;
    const int tx = threadIdx.x, ty = threadIdx.y;   // (32,8)
#pragma unroll
    for (int i = 0; i < 4; ++i)
        tile[ty + i * 8][tx] = W[(size_t)(k0 + ty + i * 8) * N + (n0 + tx)];
    __syncthreads();
#pragma unroll
    for (int i = 0; i < 4; ++i) {
        int n = n0 + ty + i * 8;
        Wt[(size_t)n * HID_ + k0 + tx] = (unsigned short)packbf(tile[tx][ty + i * 8]);
    }
}

// ---------------- bf16 MFMA GEMM: C[M,N] = A[M,K] @ Bt[N,K]^T, C f32 ----------------
// 64x64 tile, 256 thr = 4 waves (2x2), wave tile 32x32, BK=32
__global__ __launch_bounds__(256) void gemm_bf16t(const unsigned short* __restrict__ A,
                                                  const unsigned short* __restrict__ Bt,
                                                  float* __restrict__ C,
                                                  int K, int ldc) {
    __shared__ unsigned short As[64 * 32];
    __shared__ unsigned short Bs[64 * 32];
    const int tid = threadIdx.x;
    const int lane = tid & 63, wave = tid >> 6;
    const int wr = wave >> 1, wc = wave & 1;
    const int brow = blockIdx.y * 64, bcol = blockIdx.x * 64;

    f32x4 acc[2][2];
#pragma unroll
    for (int m = 0; m < 2; ++m)
#pragma unroll
        for (int n = 0; n < 2; ++n) acc[m][n] = (f32x4){0.f, 0.f, 0.f, 0.f};

    const int srow = tid >> 2, skoff = (tid & 3) * 8;
    const unsigned short* ga = A + (size_t)(brow + srow) * K + skoff;
    const unsigned short* gb = Bt + (size_t)(bcol + srow) * K + skoff;
    unsigned short* la = &As[srow * 32 + skoff];
    unsigned short* lb = &Bs[srow * 32 + skoff];

    const int l15 = lane & 15, lk = (lane >> 4) * 8;

    for (int k0 = 0; k0 < K; k0 += 32) {
        uint4 ta = *(const uint4*)(ga + k0);
        uint4 tb = *(const uint4*)(gb + k0);
        __syncthreads();
        *(uint4*)la = ta;
        *(uint4*)lb = tb;
        __syncthreads();
        bf16x8 fa[2], fb[2];
#pragma unroll
        for (int m = 0; m < 2; ++m)
            fa[m] = *(const bf16x8*)&As[(wr * 32 + m * 16 + l15) * 32 + lk];
#pragma unroll
        for (int n = 0; n < 2; ++n)
            fb[n] = *(const bf16x8*)&Bs[(wc * 32 + n * 16 + l15) * 32 + lk];
#pragma unroll
        for (int m = 0; m < 2; ++m)
#pragma unroll
            for (int n = 0; n < 2; ++n)
                acc[m][n] = __builtin_amdgcn_mfma_f32_16x16x32_bf16(fa[m], fb[n], acc[m][n], 0, 0, 0);
    }
#pragma unroll
    for (int m = 0; m < 2; ++m)
#pragma unroll
        for (int n = 0; n < 2; ++n)
#pragma unroll
            for (int q = 0; q < 4; ++q) {
                int row = brow + wr * 32 + m * 16 + (lane >> 4) * 4 + q;
                int col = bcol + wc * 32 + n * 16 + (lane & 15);
                C[(size_t)row * ldc + col] = acc[m][n][q];
            }
}

// ---------------- old tiled fp32 GEMM (used for small indexer projections) ----------------
__global__ void gemm_f32(const float* __restrict__ A, const float* __restrict__ B,
                         float* __restrict__ C, int M, int N, int K) {
    __shared__ float As2[16][64 + 1];
    __shared__ float Bs2[16][64 + 1];
    const int tid = threadIdx.x;
    const int tx = tid & 15, ty = tid >> 4;
    const int brow = blockIdx.y * 64, bcol = blockIdx.x * 64;

    float acc[4][4];
#pragma unroll
    for (int i = 0; i < 4; ++i)
#pragma unroll
        for (int j = 0; j < 4; ++j) acc[i][j] = 0.f;

    for (int k0 = 0; k0 < K; k0 += 16) {
#pragma unroll
        for (int it = 0; it < 4; ++it) {
            int i = tid + it * 256;
            int r = i >> 4, c = i & 15;
            As2[c][r] = A[(size_t)(brow + r) * K + (k0 + c)];
        }
#pragma unroll
        for (int it = 0; it < 4; ++it) {
            int i = tid + it * 256;
            int r = i >> 6, c = i & 63;
            int col = bcol + c;
            Bs2[r][c] = (col < N) ? B[(size_t)(k0 + r) * N + col] : 0.f;
        }
        __syncthreads();
#pragma unroll
        for (int kk = 0; kk < 16; ++kk) {
            float a[4], b[4];
#pragma unroll
            for (int i = 0; i < 4; ++i) a[i] = As2[kk][ty * 4 + i];
#pragma unroll
            for (int j = 0; j < 4; ++j) b[j] = Bs2[kk][tx * 4 + j];
#pragma unroll
            for (int i = 0; i < 4; ++i)
#pragma unroll
                for (int j = 0; j < 4; ++j) acc[i][j] += a[i] * b[j];
        }
        __syncthreads();
    }
#pragma unroll
    for (int i = 0; i < 4; ++i) {
        int r = brow + ty * 4 + i;
#pragma unroll
        for (int j = 0; j < 4; ++j) {
            int c = bcol + tx * 4 + j;
            if (c < N) C[(size_t)r * N + c] = acc[i][j];
        }
    }
}

// ---------------- concat indexer weights into Wi_cat [2048][164] f32 ----------------
__global__ __launch_bounds__(256) void copy_wi(const float* __restrict__ Wqi,
                                               const float* __restrict__ Wwi,
                                               const float* __restrict__ Wki,
                                               float* __restrict__ Wi) {
    int e = blockIdx.x * 256 + threadIdx.x;
    if (e >= HID_ * NIDX) return;
    int k = e / NIDX, c = e - k * NIDX;
    float v;
    if (c < 128) v = Wqi[(size_t)k * 128 + c];
    else if (c < 132) v = Wwi[(size_t)k * 4 + (c - 128)];
    else v = Wki[(size_t)k * 32 + (c - 132)];
    Wi[e] = v;
}

// ---------------- RoPE + RMSNorm q (in place in proj, f32) ----------------
__global__ void rope_rms_q(float* __restrict__ proj, const float* __restrict__ cosb,
                           const float* __restrict__ sinb) {
    const int t = blockIdx.x, h = blockIdx.y, lane = threadIdx.x;  // block 64
    float* row = proj + (size_t)t * NPROJ + h * DH;
    float a = row[lane], b = row[lane + 64];
    float c0 = cosb[t * DH + lane],      s0 = sinb[t * DH + lane];
    float c1 = cosb[t * DH + lane + 64], s1 = sinb[t * DH + lane + 64];
    float r0 = a * c0 - b * s0;
    float r1 = b * c1 + a * s1;
    float ss = r0 * r0 + r1 * r1;
#pragma unroll
    for (int o = 32; o > 0; o >>= 1) ss += __shfl_xor(ss, o);
    float inv = rsqrtf(ss * (1.0f / 128.0f) + 1.1920929e-07f);
    row[lane] = r0 * inv;
    row[lane + 64] = r1 * inv;
}

// ---------------- RoPE + RMSNorm k -> bf16 kbb ----------------
__global__ void rope_rms_k(const float* __restrict__ proj, const float* __restrict__ cosb,
                           const float* __restrict__ sinb, unsigned short* __restrict__ kbb) {
    const int t = blockIdx.x, h = blockIdx.y, lane = threadIdx.x;  // block 64
    const float* row = proj + (size_t)t * NPROJ + HID_ + h * DH;
    float a = row[lane], b = row[lane + 64];
    float c0 = cosb[t * DH + lane],      s0 = sinb[t * DH + lane];
    float c1 = cosb[t * DH + lane + 64], s1 = sinb[t * DH + lane + 64];
    float r0 = a * c0 - b * s0;
    float r1 = b * c1 + a * s1;
    float ss = r0 * r0 + r1 * r1;
#pragma unroll
    for (int o = 32; o > 0; o >>= 1) ss += __shfl_xor(ss, o);
    float inv = rsqrtf(ss * (1.0f / 128.0f) + 1.1920929e-07f);
    unsigned short* dst = kbb + ((size_t)t * NKV + h) * DH;
    dst[lane] = (unsigned short)packbf(r0 * inv);
    dst[lane + 64] = (unsigned short)packbf(r1 * inv);
}

// ---------------- cast v -> bf16 (2 elems/thread) ----------------
__global__ __launch_bounds__(256) void cast_v(const float* __restrict__ proj,
                                              unsigned int* __restrict__ vbb) {
    int e = blockIdx.x * 256 + threadIdx.x;       // 1024*256
    int t = e >> 8, c2 = e & 255;
    const float* src = proj + (size_t)t * NPROJ + HID_ + 512 + 2 * c2;
    vbb[(size_t)t * 256 + c2] = packbf(src[0]) | (packbf(src[1]) << 16);
}

// ---------------- lightning indexer scores ----------------
__global__ void indexer_kernel(const float* __restrict__ proji, float* __restrict__ S) {
    const int t = blockIdx.x;  // block 256
    __shared__ float sq[HI_][DI_];
    __shared__ float sw[HI_];
    if (threadIdx.x < HI_ * DI_)
        sq[threadIdx.x / DI_][threadIdx.x % DI_] = proji[(size_t)t * NIDX + threadIdx.x];
    if (threadIdx.x < HI_) sw[threadIdx.x] = proji[(size_t)t * NIDX + 128 + threadIdx.x];
    __syncthreads();
    for (int s = threadIdx.x; s <= t; s += 256) {
        const float* kr = proji + (size_t)s * NIDX + 132;
        float acc = 0.f;
#pragma unroll
        for (int j = 0; j < HI_; ++j) {
            float d = 0.f;
#pragma unroll
            for (int dd = 0; dd < DI_; ++dd) d += sq[j][dd] * kr[dd];
            acc += sw[j] * fmaxf(d, 0.f);
        }
        S[(size_t)t * T_ + s] = acc;
    }
}

// ---------------- single-wave exact top-256 (value desc, index asc) ----------------
__global__ void topk_wave(const float* __restrict__ S, int* __restrict__ idxout) {
    const int t = blockIdx.x, lane = threadIdx.x;   // block 64
    if (t < TOPK_) {
#pragma unroll
        for (int i = 0; i < 4; ++i) idxout[(size_t)t * TOPK_ + lane * 4 + i] = lane * 4 + i;
        return;
    }
    const int n = t + 1;
    const float* Srow = S + (size_t)t * T_;
    float v[16];
#pragma unroll
    for (int i = 0; i < 16; ++i) {
        int s = lane + (i << 6);
        v[i] = (s < n) ? Srow[s] : -INFINITY;
    }
    for (int k = 0; k < TOPK_; ++k) {
        float bv = v[0]; int bi = 0;
#pragma unroll
        for (int i = 1; i < 16; ++i)
            if (v[i] > bv) { bv = v[i]; bi = i; }
        int bs = lane + (bi << 6);
#pragma unroll
        for (int o = 32; o > 0; o >>= 1) {
            float ov = __shfl_xor(bv, o);
            int os = __shfl_xor(bs, o);
            if (ov > bv || (ov == bv && os < bs)) { bv = ov; bs = os; }
        }
        if (lane == 0) idxout[(size_t)t * TOPK_ + k] = bs;
#pragma unroll
        for (int i = 0; i < 16; ++i)
            if (lane + (i << 6) == bs) v[i] = -INFINITY;
    }
}

// ---------------- sparse GQA with LDS-staged K/V tiles ----------------
#define KSS 136   // ushort units per staged row (272B = 17*16B)
__global__ __launch_bounds__(256) void attn2(const float* __restrict__ proj,
                                             const unsigned short* __restrict__ kbb,
                                             const unsigned short* __restrict__ vbb,
                                             const int* __restrict__ idx,
                                             unsigned short* __restrict__ attnb) {
    const int t = blockIdx.x, n = blockIdx.y;
    const int tid = threadIdx.x, lane = tid & 63, w = tid >> 6;
    const int C = (t + 1 < TOPK_) ? t + 1 : TOPK_;

    __shared__ float Qs[4][128];
    __shared__ unsigned short Ks[64 * KSS];
    __shared__ float sp[4][TOPK_];
    __shared__ int sidx[TOPK_];

    sidx[tid] = idx[(size_t)t * TOPK_ + tid];
    {
        const float* qbase = proj + (size_t)t * NPROJ + n * 512;
        Qs[tid >> 7][tid & 127] = qbase[tid];
        Qs[(tid + 256) >> 7][tid & 127] = qbase[tid + 256];
    }
    __syncthreads();

    const int srow = tid >> 2;            // staging: 4 iters, chunk c = tid + it*256
    float sc[4];
#pragma unroll 1
    for (int tau = 0; tau < 4; ++tau) {
        // stage 64 K rows (bf16) into Ks
#pragma unroll
        for (int it = 0; it < 4; ++it) {
            int c = tid + it * 256;
            int r = c >> 4, off = (c & 15) * 8;
            int s = sidx[tau * 64 + r];
            *(uint4*)&Ks[r * KSS + off] = *(const uint4*)&kbb[((size_t)s * NKV + n) * DH + off];
        }
        __syncthreads();
        int j = tau * 64 + lane;
        float acc = 0.f;
        const unsigned short* kr = &Ks[lane * KSS];
#pragma unroll
        for (int d0 = 0; d0 < 16; ++d0) {
            uint4 kv = *(const uint4*)(kr + d0 * 8);
            const float* qp = &Qs[w][d0 * 8];
            float4 q0 = *(const float4*)qp;
            float4 q1 = *(const float4*)(qp + 4);
            acc += bflo(kv.x) * q0.x + bfhi(kv.x) * q0.y
                 + bflo(kv.y) * q0.z + bfhi(kv.y) * q0.w
                 + bflo(kv.z) * q1.x + bfhi(kv.z) * q1.y
                 + bflo(kv.w) * q1.z + bfhi(kv.w) * q1.w;
        }
        sc[tau] = (j < C) ? acc * 0.08838834764831845f : -INFINITY;
        __syncthreads();
    }
    // wave softmax over 256 slots
    float m = fmaxf(fmaxf(sc[0], sc[1]), fmaxf(sc[2], sc[3]));
#pragma unroll
    for (int o = 32; o > 0; o >>= 1) m = fmaxf(m, __shfl_xor(m, o));
    float sum = 0.f;
#pragma unroll
    for (int tau = 0; tau < 4; ++tau) {
        float e = expf(sc[tau] - m);       // exp(-inf) = 0 for masked
        sp[w][tau * 64 + lane] = e;
        sum += e;
    }
#pragma unroll
    for (int o = 32; o > 0; o >>= 1) sum += __shfl_xor(sum, o);
    float inv = 1.f / sum;

    // PV: lane owns dims 2*lane, 2*lane+1
    float o0 = 0.f, o1 = 0.f;
#pragma unroll 1
    for (int tau = 0; tau < 4; ++tau) {
#pragma unroll
        for (int it = 0; it < 4; ++it) {
            int c = tid + it * 256;
            int r = c >> 4, off = (c & 15) * 8;
            int s = sidx[tau * 64 + r];
            *(uint4*)&Ks[r * KSS + off] = *(const uint4*)&vbb[((size_t)s * NKV + n) * DH + off];
        }
        __syncthreads();
        const float* pw = &sp[w][tau * 64];
        const unsigned short* vb0 = &Ks[2 * lane];
#pragma unroll
        for (int jj = 0; jj < 64; ++jj) {
            float p = pw[jj];
            unsigned int uv = *(const unsigned int*)(vb0 + jj * KSS);
            o0 += p * bflo(uv);
            o1 += p * bfhi(uv);
        }
        __syncthreads();
    }
    o0 *= inv; o1 *= inv;
    unsigned int res = packbf(o0) | (packbf(o1) << 16);
    *(unsigned int*)&attnb[(size_t)t * HID_ + (n * 4 + w) * DH + 2 * lane] = res;
}

// ---------------- launch ----------------
extern "C" void kernel_launch(void* const* d_in, const int* in_sizes, int n_in,
                              void* d_out, int out_size, void* d_ws, size_t ws_size,
                              hipStream_t stream) {
    const float* x    = (const float*)d_in[0];
    const float* cosb = (const float*)d_in[1];
    const float* sinb = (const float*)d_in[2];
    const float* Wq   = (const float*)d_in[3];
    const float* Wk   = (const float*)d_in[4];
    const float* Wv   = (const float*)d_in[5];
    const float* Wo   = (const float*)d_in[6];
    const float* Wqi  = (const float*)d_in[7];
    const float* Wwi  = (const float*)d_in[8];
    const float* Wki  = (const float*)d_in[9];
    float* out = (float*)d_out;

    unsigned short* xb    = (unsigned short*)d_ws;             // 1024*2048 bf16
    unsigned short* WtAll = xb + 2097152;                      // 3072*2048 bf16
    float*  proj  = (float*)(WtAll + 6291456);                 // 1024*3072 f32
    float*  Wi    = proj + 3145728;                            // 2048*164 f32
    float*  proji = Wi + 335872;                               // 1024*164 f32
    float*  S     = proji + 167936;                            // 1024*1024 f32
    int*    idxb  = (int*)(S + 1048576);                       // 1024*256 int
    unsigned short* kbb   = (unsigned short*)(idxb + 262144);  // 1024*512 bf16
    unsigned short* vbb   = kbb + 524288;                      // 1024*512 bf16
    unsigned short* attnb = vbb + 524288;                      // 1024*2048 bf16
    unsigned short* Wot   = WtAll;                             // reuse after proj GEMM

    // casts / transposes
    cast_x<<<dim3(1024), dim3(256), 0, stream>>>(x, xb, 262144);
    tcast<<<dim3(64, 64), dim3(32, 8), 0, stream>>>(Wq, WtAll, HID_);
    tcast<<<dim3(16, 64), dim3(32, 8), 0, stream>>>(Wk, WtAll + (size_t)2048 * HID_, 512);
    tcast<<<dim3(16, 64), dim3(32, 8), 0, stream>>>(Wv, WtAll + (size_t)2560 * HID_, 512);
    copy_wi<<<dim3((HID_ * NIDX + 255) / 256), dim3(256), 0, stream>>>(Wqi, Wwi, Wki, Wi);

    // projections
    gemm_bf16t<<<dim3(NPROJ / 64, T_ / 64), dim3(256), 0, stream>>>(xb, WtAll, proj, HID_, NPROJ);
    gemm_f32<<<dim3((NIDX + 63) / 64, T_ / 64), dim3(256), 0, stream>>>(x, Wi, proji, T_, NIDX, HID_);

    // Wo transpose can reuse WtAll space now
    tcast<<<dim3(64, 64), dim3(32, 8), 0, stream>>>(Wo, Wot, HID_);

    // rope + rms, v cast
    rope_rms_q<<<dim3(T_, NH), dim3(64), 0, stream>>>(proj, cosb, sinb);
    rope_rms_k<<<dim3(T_, NKV), dim3(64), 0, stream>>>(proj, cosb, sinb, kbb);
    cast_v<<<dim3(1024), dim3(256), 0, stream>>>(proj, (unsigned int*)vbb);

    // indexer scores + topk
    indexer_kernel<<<dim3(T_), dim3(256), 0, stream>>>(proji, S);
    topk_wave<<<dim3(T_), dim3(64), 0, stream>>>(S, idxb);

    // sparse attention
    attn2<<<dim3(T_, NKV), dim3(256), 0, stream>>>(proj, kbb, vbb, idxb, attnb);

    // output projection
    gemm_bf16t<<<dim3(HID_ / 64, T_ / 64), dim3(256), 0, stream>>>(attnb, Wot, out, HID_, HID_);
}

// Round 3
// 455.605 us; speedup vs baseline: 5.7601x; 1.7315x over previous
//
#include <hip/hip_runtime.h>
#include <hip/hip_bf16.h>
#include <math.h>

#define T_    1024
#define HID_  2048
#define NH    16
#define NKV   4
#define DH    128
#define TOPK_ 256
#define HI_   4
#define DI_   32
#define NPROJ 3072          // q(2048) + k(512) + v(512)
#define NIDX  164           // qi(128) + wi(4) + ki(32)
#define KSPLIT 8
#define KCHUNK 256

#ifndef INFINITY
#define INFINITY (__builtin_inff())
#endif

typedef __attribute__((ext_vector_type(8))) short bf16x8;
typedef __attribute__((ext_vector_type(4))) float f32x4;

__device__ inline float bflo(unsigned int u) { return __uint_as_float(u << 16); }
__device__ inline float bfhi(unsigned int u) { return __uint_as_float(u & 0xffff0000u); }
__device__ inline unsigned int packbf(float f) {   // RNE f32->bf16 (bits in low 16)
    unsigned int u = __float_as_uint(f);
    return (u + 0x7fffu + ((u >> 16) & 1u)) >> 16;
}

// ---------------- cast x f32 -> bf16 (8 elems/thread) ----------------
__global__ __launch_bounds__(256) void cast_x(const float* __restrict__ in,
                                              unsigned short* __restrict__ outb, int n8) {
    int e = blockIdx.x * 256 + threadIdx.x;
    if (e >= n8) return;
    const float4* p = (const float4*)(in + (size_t)e * 8);
    float4 a = p[0], b = p[1];
    uint4 r;
    r.x = packbf(a.x) | (packbf(a.y) << 16);
    r.y = packbf(a.z) | (packbf(a.w) << 16);
    r.z = packbf(b.x) | (packbf(b.y) << 16);
    r.w = packbf(b.z) | (packbf(b.w) << 16);
    *(uint4*)(outb + (size_t)e * 8) = r;
}

// ---------------- transpose+cast W [K=2048][N] f32 -> Wt [N][2048] bf16 ----------------
__global__ void tcast(const float* __restrict__ W, unsigned short* __restrict__ Wt, int N) {
    __shared__ float tile[32][33];
    const int n0 = blockIdx.x * 32, k0 = blockIdx.y * 32;
    const int tx = threadIdx.x, ty = threadIdx.y;   // (32,8)
#pragma unroll
    for (int i = 0; i < 4; ++i)
        tile[ty + i * 8][tx] = W[(size_t)(k0 + ty + i * 8) * N + (n0 + tx)];
    __syncthreads();
#pragma unroll
    for (int i = 0; i < 4; ++i) {
        int n = n0 + ty + i * 8;
        Wt[(size_t)n * HID_ + k0 + tx] = (unsigned short)packbf(tile[tx][ty + i * 8]);
    }
}

// ---------------- bf16 MFMA GEMM: C[M,N] = A[M,K] @ Bt[N,K]^T, C f32 ----------------
__global__ __launch_bounds__(256) void gemm_bf16t(const unsigned short* __restrict__ A,
                                                  const unsigned short* __restrict__ Bt,
                                                  float* __restrict__ C,
                                                  int K, int ldc) {
    __shared__ unsigned short As[64 * 32];
    __shared__ unsigned short Bs[64 * 32];
    const int tid = threadIdx.x;
    const int lane = tid & 63, wave = tid >> 6;
    const int wr = wave >> 1, wc = wave & 1;
    const int brow = blockIdx.y * 64, bcol = blockIdx.x * 64;

    f32x4 acc[2][2];
#pragma unroll
    for (int m = 0; m < 2; ++m)
#pragma unroll
        for (int n = 0; n < 2; ++n) acc[m][n] = (f32x4){0.f, 0.f, 0.f, 0.f};

    const int srow = tid >> 2, skoff = (tid & 3) * 8;
    const unsigned short* ga = A + (size_t)(brow + srow) * K + skoff;
    const unsigned short* gb = Bt + (size_t)(bcol + srow) * K + skoff;
    unsigned short* la = &As[srow * 32 + skoff];
    unsigned short* lb = &Bs[srow * 32 + skoff];

    const int l15 = lane & 15, lk = (lane >> 4) * 8;

    for (int k0 = 0; k0 < K; k0 += 32) {
        uint4 ta = *(const uint4*)(ga + k0);
        uint4 tb = *(const uint4*)(gb + k0);
        __syncthreads();
        *(uint4*)la = ta;
        *(uint4*)lb = tb;
        __syncthreads();
        bf16x8 fa[2], fb[2];
#pragma unroll
        for (int m = 0; m < 2; ++m)
            fa[m] = *(const bf16x8*)&As[(wr * 32 + m * 16 + l15) * 32 + lk];
#pragma unroll
        for (int n = 0; n < 2; ++n)
            fb[n] = *(const bf16x8*)&Bs[(wc * 32 + n * 16 + l15) * 32 + lk];
#pragma unroll
        for (int m = 0; m < 2; ++m)
#pragma unroll
            for (int n = 0; n < 2; ++n)
                acc[m][n] = __builtin_amdgcn_mfma_f32_16x16x32_bf16(fa[m], fb[n], acc[m][n], 0, 0, 0);
    }
#pragma unroll
    for (int m = 0; m < 2; ++m)
#pragma unroll
        for (int n = 0; n < 2; ++n)
#pragma unroll
            for (int q = 0; q < 4; ++q) {
                int row = brow + wr * 32 + m * 16 + (lane >> 4) * 4 + q;
                int col = bcol + wc * 32 + n * 16 + (lane & 15);
                C[(size_t)row * ldc + col] = acc[m][n][q];
            }
}

// ---------------- split-K fp32 GEMM for indexer projection ----------------
// grid (N/64, M/64, KSPLIT); each z covers K chunk [z*KCHUNK, (z+1)*KCHUNK)
__global__ void gemm_f32_splitk(const float* __restrict__ A, const float* __restrict__ B,
                                float* __restrict__ Cpart, int M, int N, int K) {
    __shared__ float As2[16][64 + 1];
    __shared__ float Bs2[16][64 + 1];
    const int tid = threadIdx.x;
    const int tx = tid & 15, ty = tid >> 4;
    const int brow = blockIdx.y * 64, bcol = blockIdx.x * 64;
    const int z = blockIdx.z;
    const int kbeg = z * KCHUNK, kend = kbeg + KCHUNK;

    float acc[4][4];
#pragma unroll
    for (int i = 0; i < 4; ++i)
#pragma unroll
        for (int j = 0; j < 4; ++j) acc[i][j] = 0.f;

    for (int k0 = kbeg; k0 < kend; k0 += 16) {
#pragma unroll
        for (int it = 0; it < 4; ++it) {
            int i = tid + it * 256;
            int r = i >> 4, c = i & 15;
            As2[c][r] = A[(size_t)(brow + r) * K + (k0 + c)];
        }
#pragma unroll
        for (int it = 0; it < 4; ++it) {
            int i = tid + it * 256;
            int r = i >> 6, c = i & 63;
            int col = bcol + c;
            Bs2[r][c] = (col < N) ? B[(size_t)(k0 + r) * N + col] : 0.f;
        }
        __syncthreads();
#pragma unroll
        for (int kk = 0; kk < 16; ++kk) {
            float a[4], b[4];
#pragma unroll
            for (int i = 0; i < 4; ++i) a[i] = As2[kk][ty * 4 + i];
#pragma unroll
            for (int j = 0; j < 4; ++j) b[j] = Bs2[kk][tx * 4 + j];
#pragma unroll
            for (int i = 0; i < 4; ++i)
#pragma unroll
                for (int j = 0; j < 4; ++j) acc[i][j] += a[i] * b[j];
        }
        __syncthreads();
    }
#pragma unroll
    for (int i = 0; i < 4; ++i) {
        int r = brow + ty * 4 + i;
#pragma unroll
        for (int j = 0; j < 4; ++j) {
            int c = bcol + tx * 4 + j;
            if (c < N) Cpart[((size_t)z * M + r) * N + c] = acc[i][j];
        }
    }
}

// ---------------- reduce split-K partials (fixed order => deterministic) ----------------
__global__ __launch_bounds__(256) void reduce_k(const float* __restrict__ Cpart,
                                                float* __restrict__ Cout, int MN) {
    int e = blockIdx.x * 256 + threadIdx.x;
    if (e >= MN) return;
    float s = 0.f;
#pragma unroll
    for (int z = 0; z < KSPLIT; ++z) s += Cpart[(size_t)z * MN + e];
    Cout[e] = s;
}

// ---------------- concat indexer weights into Wi_cat [2048][164] f32 ----------------
__global__ __launch_bounds__(256) void copy_wi(const float* __restrict__ Wqi,
                                               const float* __restrict__ Wwi,
                                               const float* __restrict__ Wki,
                                               float* __restrict__ Wi) {
    int e = blockIdx.x * 256 + threadIdx.x;
    if (e >= HID_ * NIDX) return;
    int k = e / NIDX, c = e - k * NIDX;
    float v;
    if (c < 128) v = Wqi[(size_t)k * 128 + c];
    else if (c < 132) v = Wwi[(size_t)k * 4 + (c - 128)];
    else v = Wki[(size_t)k * 32 + (c - 132)];
    Wi[e] = v;
}

// ---------------- RoPE + RMSNorm q (in place in proj, f32) ----------------
__global__ void rope_rms_q(float* __restrict__ proj, const float* __restrict__ cosb,
                           const float* __restrict__ sinb) {
    const int t = blockIdx.x, h = blockIdx.y, lane = threadIdx.x;  // block 64
    float* row = proj + (size_t)t * NPROJ + h * DH;
    float a = row[lane], b = row[lane + 64];
    float c0 = cosb[t * DH + lane],      s0 = sinb[t * DH + lane];
    float c1 = cosb[t * DH + lane + 64], s1 = sinb[t * DH + lane + 64];
    float r0 = a * c0 - b * s0;
    float r1 = b * c1 + a * s1;
    float ss = r0 * r0 + r1 * r1;
#pragma unroll
    for (int o = 32; o > 0; o >>= 1) ss += __shfl_xor(ss, o);
    float inv = rsqrtf(ss * (1.0f / 128.0f) + 1.1920929e-07f);
    row[lane] = r0 * inv;
    row[lane + 64] = r1 * inv;
}

// ---------------- RoPE + RMSNorm k -> bf16 kbb ----------------
__global__ void rope_rms_k(const float* __restrict__ proj, const float* __restrict__ cosb,
                           const float* __restrict__ sinb, unsigned short* __restrict__ kbb) {
    const int t = blockIdx.x, h = blockIdx.y, lane = threadIdx.x;  // block 64
    const float* row = proj + (size_t)t * NPROJ + HID_ + h * DH;
    float a = row[lane], b = row[lane + 64];
    float c0 = cosb[t * DH + lane],      s0 = sinb[t * DH + lane];
    float c1 = cosb[t * DH + lane + 64], s1 = sinb[t * DH + lane + 64];
    float r0 = a * c0 - b * s0;
    float r1 = b * c1 + a * s1;
    float ss = r0 * r0 + r1 * r1;
#pragma unroll
    for (int o = 32; o > 0; o >>= 1) ss += __shfl_xor(ss, o);
    float inv = rsqrtf(ss * (1.0f / 128.0f) + 1.1920929e-07f);
    unsigned short* dst = kbb + ((size_t)t * NKV + h) * DH;
    dst[lane] = (unsigned short)packbf(r0 * inv);
    dst[lane + 64] = (unsigned short)packbf(r1 * inv);
}

// ---------------- cast v -> bf16 (2 elems/thread) ----------------
__global__ __launch_bounds__(256) void cast_v(const float* __restrict__ proj,
                                              unsigned int* __restrict__ vbb) {
    int e = blockIdx.x * 256 + threadIdx.x;       // 1024*256
    int t = e >> 8, c2 = e & 255;
    const float* src = proj + (size_t)t * NPROJ + HID_ + 512 + 2 * c2;
    vbb[(size_t)t * 256 + c2] = packbf(src[0]) | (packbf(src[1]) << 16);
}

// ---------------- tiled lightning indexer: 64x64 (t,s) tiles, fp32 ----------------
__global__ __launch_bounds__(256) void indexer_tiled(const float* __restrict__ proji,
                                                     float* __restrict__ S) {
    const int sb = blockIdx.x, tb = blockIdx.y;
    if (sb > tb) return;                     // strictly above diagonal: no valid s<=t
    __shared__ float qs[64][132];            // qi rows (padded)
    __shared__ float wsm[64][4];             // wi
    __shared__ float ks[64][36];             // ki rows (padded)
    const int tid = threadIdx.x;

    // stage qi (64x128 f32) as float4
#pragma unroll
    for (int it = 0; it < 8; ++it) {
        int i = tid + it * 256;              // 0..2047 float4 chunks
        int r = i >> 5, c4 = i & 31;
        *(float4*)&qs[r][c4 * 4] = *(const float4*)&proji[(size_t)(tb * 64 + r) * NIDX + c4 * 4];
    }
    {   // wi: 64x4
        int r = tid >> 2, j = tid & 3;
        wsm[r][j] = proji[(size_t)(tb * 64 + r) * NIDX + 128 + j];
    }
#pragma unroll
    for (int it = 0; it < 2; ++it) {         // ki: 64x32 as float4
        int i = tid + it * 256;
        int r = i >> 3, c4 = i & 7;
        *(float4*)&ks[r][c4 * 4] = *(const float4*)&proji[(size_t)(sb * 64 + r) * NIDX + 132 + c4 * 4];
    }
    __syncthreads();

    const int tx = tid & 15, ty = tid >> 4;  // s-dim, t-dim
    float out[4][4] = {};
#pragma unroll
    for (int j = 0; j < HI_; ++j) {
        float acc[4][4] = {};
#pragma unroll
        for (int d4 = 0; d4 < 8; ++d4) {
            float4 a[4], b[4];
#pragma unroll
            for (int i = 0; i < 4; ++i) a[i] = *(const float4*)&qs[ty + i * 16][j * 32 + d4 * 4];
#pragma unroll
            for (int jj = 0; jj < 4; ++jj) b[jj] = *(const float4*)&ks[tx + jj * 16][d4 * 4];
#pragma unroll
            for (int i = 0; i < 4; ++i)
#pragma unroll
                for (int jj = 0; jj < 4; ++jj)
                    acc[i][jj] += a[i].x * b[jj].x + a[i].y * b[jj].y +
                                  a[i].z * b[jj].z + a[i].w * b[jj].w;
        }
#pragma unroll
        for (int i = 0; i < 4; ++i) {
            float w = wsm[ty + i * 16][j];
#pragma unroll
            for (int jj = 0; jj < 4; ++jj)
                out[i][jj] += w * fmaxf(acc[i][jj], 0.f);
        }
    }
#pragma unroll
    for (int i = 0; i < 4; ++i) {
        int t = tb * 64 + ty + i * 16;
#pragma unroll
        for (int jj = 0; jj < 4; ++jj) {
            int s = sb * 64 + tx + jj * 16;
            if (s <= t) S[(size_t)t * T_ + s] = out[i][jj];
        }
    }
}

// ---------------- single-wave exact top-256 (value desc, index asc) ----------------
__global__ void topk_wave(const float* __restrict__ S, int* __restrict__ idxout) {
    const int t = blockIdx.x, lane = threadIdx.x;   // block 64
    if (t < TOPK_) {
#pragma unroll
        for (int i = 0; i < 4; ++i) idxout[(size_t)t * TOPK_ + lane * 4 + i] = lane * 4 + i;
        return;
    }
    const int n = t + 1;
    const float* Srow = S + (size_t)t * T_;
    float v[16];
#pragma unroll
    for (int i = 0; i < 16; ++i) {
        int s = lane + (i << 6);
        v[i] = (s < n) ? Srow[s] : -INFINITY;
    }
    for (int k = 0; k < TOPK_; ++k) {
        float bv = v[0]; int bi = 0;
#pragma unroll
        for (int i = 1; i < 16; ++i)
            if (v[i] > bv) { bv = v[i]; bi = i; }
        int bs = lane + (bi << 6);
#pragma unroll
        for (int o = 32; o > 0; o >>= 1) {
            float ov = __shfl_xor(bv, o);
            int os = __shfl_xor(bs, o);
            if (ov > bv || (ov == bv && os < bs)) { bv = ov; bs = os; }
        }
        if (lane == 0) idxout[(size_t)t * TOPK_ + k] = bs;
#pragma unroll
        for (int i = 0; i < 16; ++i)
            if (lane + (i << 6) == bs) v[i] = -INFINITY;
    }
}

// ---------------- sparse GQA with LDS-staged K/V tiles ----------------
#define KSS 136   // ushort units per staged row (272B = 17*16B)
__global__ __launch_bounds__(256) void attn2(const float* __restrict__ proj,
                                             const unsigned short* __restrict__ kbb,
                                             const unsigned short* __restrict__ vbb,
                                             const int* __restrict__ idx,
                                             unsigned short* __restrict__ attnb) {
    const int t = blockIdx.x, n = blockIdx.y;
    const int tid = threadIdx.x, lane = tid & 63, w = tid >> 6;
    const int C = (t + 1 < TOPK_) ? t + 1 : TOPK_;

    __shared__ float Qs[4][128];
    __shared__ unsigned short Ks[64 * KSS];
    __shared__ float sp[4][TOPK_];
    __shared__ int sidx[TOPK_];

    sidx[tid] = idx[(size_t)t * TOPK_ + tid];
    {
        const float* qbase = proj + (size_t)t * NPROJ + n * 512;
        Qs[tid >> 7][tid & 127] = qbase[tid];
        Qs[(tid + 256) >> 7][tid & 127] = qbase[tid + 256];
    }
    __syncthreads();

    float sc[4];
#pragma unroll 1
    for (int tau = 0; tau < 4; ++tau) {
#pragma unroll
        for (int it = 0; it < 4; ++it) {
            int c = tid + it * 256;
            int r = c >> 4, off = (c & 15) * 8;
            int s = sidx[tau * 64 + r];
            *(uint4*)&Ks[r * KSS + off] = *(const uint4*)&kbb[((size_t)s * NKV + n) * DH + off];
        }
        __syncthreads();
        int j = tau * 64 + lane;
        float acc = 0.f;
        const unsigned short* kr = &Ks[lane * KSS];
#pragma unroll
        for (int d0 = 0; d0 < 16; ++d0) {
            uint4 kv = *(const uint4*)(kr + d0 * 8);
            const float* qp = &Qs[w][d0 * 8];
            float4 q0 = *(const float4*)qp;
            float4 q1 = *(const float4*)(qp + 4);
            acc += bflo(kv.x) * q0.x + bfhi(kv.x) * q0.y
                 + bflo(kv.y) * q0.z + bfhi(kv.y) * q0.w
                 + bflo(kv.z) * q1.x + bfhi(kv.z) * q1.y
                 + bflo(kv.w) * q1.z + bfhi(kv.w) * q1.w;
        }
        sc[tau] = (j < C) ? acc * 0.08838834764831845f : -INFINITY;
        __syncthreads();
    }
    float m = fmaxf(fmaxf(sc[0], sc[1]), fmaxf(sc[2], sc[3]));
#pragma unroll
    for (int o = 32; o > 0; o >>= 1) m = fmaxf(m, __shfl_xor(m, o));
    float sum = 0.f;
#pragma unroll
    for (int tau = 0; tau < 4; ++tau) {
        float e = expf(sc[tau] - m);
        sp[w][tau * 64 + lane] = e;
        sum += e;
    }
#pragma unroll
    for (int o = 32; o > 0; o >>= 1) sum += __shfl_xor(sum, o);
    float inv = 1.f / sum;

    float o0 = 0.f, o1 = 0.f;
#pragma unroll 1
    for (int tau = 0; tau < 4; ++tau) {
#pragma unroll
        for (int it = 0; it < 4; ++it) {
            int c = tid + it * 256;
            int r = c >> 4, off = (c & 15) * 8;
            int s = sidx[tau * 64 + r];
            *(uint4*)&Ks[r * KSS + off] = *(const uint4*)&vbb[((size_t)s * NKV + n) * DH + off];
        }
        __syncthreads();
        const float* pw = &sp[w][tau * 64];
        const unsigned short* vb0 = &Ks[2 * lane];
#pragma unroll
        for (int jj = 0; jj < 64; ++jj) {
            float p = pw[jj];
            unsigned int uv = *(const unsigned int*)(vb0 + jj * KSS);
            o0 += p * bflo(uv);
            o1 += p * bfhi(uv);
        }
        __syncthreads();
    }
    o0 *= inv; o1 *= inv;
    unsigned int res = packbf(o0) | (packbf(o1) << 16);
    *(unsigned int*)&attnb[(size_t)t * HID_ + (n * 4 + w) * DH + 2 * lane] = res;
}

// ---------------- launch ----------------
extern "C" void kernel_launch(void* const* d_in, const int* in_sizes, int n_in,
                              void* d_out, int out_size, void* d_ws, size_t ws_size,
                              hipStream_t stream) {
    const float* x    = (const float*)d_in[0];
    const float* cosb = (const float*)d_in[1];
    const float* sinb = (const float*)d_in[2];
    const float* Wq   = (const float*)d_in[3];
    const float* Wk   = (const float*)d_in[4];
    const float* Wv   = (const float*)d_in[5];
    const float* Wo   = (const float*)d_in[6];
    const float* Wqi  = (const float*)d_in[7];
    const float* Wwi  = (const float*)d_in[8];
    const float* Wki  = (const float*)d_in[9];
    float* out = (float*)d_out;

    unsigned short* xb    = (unsigned short*)d_ws;             // 1024*2048 bf16
    unsigned short* WtAll = xb + 2097152;                      // 3072*2048 bf16
    float*  proj  = (float*)(WtAll + 6291456);                 // 1024*3072 f32
    float*  Wi    = proj + 3145728;                            // 2048*164 f32
    float*  proji = Wi + 335872;                               // 1024*164 f32
    float*  S     = proji + 167936;                            // 1024*1024 f32
    int*    idxb  = (int*)(S + 1048576);                       // 1024*256 int
    unsigned short* kbb   = (unsigned short*)(idxb + 262144);  // 1024*512 bf16
    unsigned short* vbb   = kbb + 524288;                      // 1024*512 bf16
    unsigned short* attnb = vbb + 524288;                      // 1024*2048 bf16
    unsigned short* Wot   = WtAll;                             // reuse after proj GEMM
    // split-K partials (8*1024*164 f32 = 5.4MB) overlap kbb/vbb/attnb region:
    // they are consumed by reduce_k BEFORE kbb/vbb/attnb are written.
    float* Cpart = (float*)kbb;

    // casts / transposes
    cast_x<<<dim3(1024), dim3(256), 0, stream>>>(x, xb, 262144);
    tcast<<<dim3(64, 64), dim3(32, 8), 0, stream>>>(Wq, WtAll, HID_);
    tcast<<<dim3(16, 64), dim3(32, 8), 0, stream>>>(Wk, WtAll + (size_t)2048 * HID_, 512);
    tcast<<<dim3(16, 64), dim3(32, 8), 0, stream>>>(Wv, WtAll + (size_t)2560 * HID_, 512);
    copy_wi<<<dim3((HID_ * NIDX + 255) / 256), dim3(256), 0, stream>>>(Wqi, Wwi, Wki, Wi);

    // projections
    gemm_bf16t<<<dim3(NPROJ / 64, T_ / 64), dim3(256), 0, stream>>>(xb, WtAll, proj, HID_, NPROJ);
    gemm_f32_splitk<<<dim3((NIDX + 63) / 64, T_ / 64, KSPLIT), dim3(256), 0, stream>>>(x, Wi, Cpart, T_, NIDX, HID_);
    reduce_k<<<dim3((T_ * NIDX + 255) / 256), dim3(256), 0, stream>>>(Cpart, proji, T_ * NIDX);

    // Wo transpose can reuse WtAll space now
    tcast<<<dim3(64, 64), dim3(32, 8), 0, stream>>>(Wo, Wot, HID_);

    // rope + rms, v cast (kbb/vbb written only after Cpart is dead)
    rope_rms_q<<<dim3(T_, NH), dim3(64), 0, stream>>>(proj, cosb, sinb);
    rope_rms_k<<<dim3(T_, NKV), dim3(64), 0, stream>>>(proj, cosb, sinb, kbb);
    cast_v<<<dim3(1024), dim3(256), 0, stream>>>(proj, (unsigned int*)vbb);

    // indexer scores + topk
    indexer_tiled<<<dim3(16, 16), dim3(256), 0, stream>>>(proji, S);
    topk_wave<<<dim3(T_), dim3(64), 0, stream>>>(S, idxb);

    // sparse attention
    attn2<<<dim3(T_, NKV), dim3(256), 0, stream>>>(proj, kbb, vbb, idxb, attnb);

    // output projection
    gemm_bf16t<<<dim3(HID_ / 64, T_ / 64), dim3(256), 0, stream>>>(attnb, Wot, out, HID_, HID_);
}

// Round 4
// 282.247 us; speedup vs baseline: 9.2981x; 1.6142x over previous
//
#include <hip/hip_runtime.h>
#include <hip/hip_bf16.h>
#include <math.h>

#define T_    1024
#define HID_  2048
#define NH    16
#define NKV   4
#define DH    128
#define TOPK_ 256
#define HI_   4
#define DI_   32
#define NPROJ 3072          // q(2048) + k(512) + v(512)
#define NIDX  164           // qi(128) + wi(4) + ki(32)
#define KSPLIT 8
#define KCHUNK 256

#ifndef INFINITY
#define INFINITY (__builtin_inff())
#endif

typedef __attribute__((ext_vector_type(8))) short bf16x8;
typedef __attribute__((ext_vector_type(4))) float f32x4;

__device__ inline float bflo(unsigned int u) { return __uint_as_float(u << 16); }
__device__ inline float bfhi(unsigned int u) { return __uint_as_float(u & 0xffff0000u); }
__device__ inline unsigned int packbf(float f) {   // RNE f32->bf16 (bits in low 16)
    unsigned int u = __float_as_uint(f);
    return (u + 0x7fffu + ((u >> 16) & 1u)) >> 16;
}

// ---------------- cast x f32 -> bf16 (8 elems/thread) ----------------
__global__ __launch_bounds__(256) void cast_x(const float* __restrict__ in,
                                              unsigned short* __restrict__ outb, int n8) {
    int e = blockIdx.x * 256 + threadIdx.x;
    if (e >= n8) return;
    const float4* p = (const float4*)(in + (size_t)e * 8);
    float4 a = p[0], b = p[1];
    uint4 r;
    r.x = packbf(a.x) | (packbf(a.y) << 16);
    r.y = packbf(a.z) | (packbf(a.w) << 16);
    r.z = packbf(b.x) | (packbf(b.y) << 16);
    r.w = packbf(b.z) | (packbf(b.w) << 16);
    *(uint4*)(outb + (size_t)e * 8) = r;
}

// ---------------- transpose+cast W [K=2048][N] f32 -> Wt [N][2048] bf16 ----------------
__global__ void tcast(const float* __restrict__ W, unsigned short* __restrict__ Wt, int N) {
    __shared__ float tile[32][33];
    const int n0 = blockIdx.x * 32, k0 = blockIdx.y * 32;
    const int tx = threadIdx.x, ty = threadIdx.y;   // (32,8)
#pragma unroll
    for (int i = 0; i < 4; ++i)
        tile[ty + i * 8][tx] = W[(size_t)(k0 + ty + i * 8) * N + (n0 + tx)];
    __syncthreads();
#pragma unroll
    for (int i = 0; i < 4; ++i) {
        int n = n0 + ty + i * 8;
        Wt[(size_t)n * HID_ + k0 + tx] = (unsigned short)packbf(tile[tx][ty + i * 8]);
    }
}

// ---------------- bf16 MFMA GEMM: C[M,N] = A[M,K] @ Bt[N,K]^T, C f32 ----------------
__global__ __launch_bounds__(256) void gemm_bf16t(const unsigned short* __restrict__ A,
                                                  const unsigned short* __restrict__ Bt,
                                                  float* __restrict__ C,
                                                  int K, int ldc) {
    __shared__ unsigned short As[64 * 32];
    __shared__ unsigned short Bs[64 * 32];
    const int tid = threadIdx.x;
    const int lane = tid & 63, wave = tid >> 6;
    const int wr = wave >> 1, wc = wave & 1;
    const int brow = blockIdx.y * 64, bcol = blockIdx.x * 64;

    f32x4 acc[2][2];
#pragma unroll
    for (int m = 0; m < 2; ++m)
#pragma unroll
        for (int n = 0; n < 2; ++n) acc[m][n] = (f32x4){0.f, 0.f, 0.f, 0.f};

    const int srow = tid >> 2, skoff = (tid & 3) * 8;
    const unsigned short* ga = A + (size_t)(brow + srow) * K + skoff;
    const unsigned short* gb = Bt + (size_t)(bcol + srow) * K + skoff;
    unsigned short* la = &As[srow * 32 + skoff];
    unsigned short* lb = &Bs[srow * 32 + skoff];

    const int l15 = lane & 15, lk = (lane >> 4) * 8;

    for (int k0 = 0; k0 < K; k0 += 32) {
        uint4 ta = *(const uint4*)(ga + k0);
        uint4 tb = *(const uint4*)(gb + k0);
        __syncthreads();
        *(uint4*)la = ta;
        *(uint4*)lb = tb;
        __syncthreads();
        bf16x8 fa[2], fb[2];
#pragma unroll
        for (int m = 0; m < 2; ++m)
            fa[m] = *(const bf16x8*)&As[(wr * 32 + m * 16 + l15) * 32 + lk];
#pragma unroll
        for (int n = 0; n < 2; ++n)
            fb[n] = *(const bf16x8*)&Bs[(wc * 32 + n * 16 + l15) * 32 + lk];
#pragma unroll
        for (int m = 0; m < 2; ++m)
#pragma unroll
            for (int n = 0; n < 2; ++n)
                acc[m][n] = __builtin_amdgcn_mfma_f32_16x16x32_bf16(fa[m], fb[n], acc[m][n], 0, 0, 0);
    }
#pragma unroll
    for (int m = 0; m < 2; ++m)
#pragma unroll
        for (int n = 0; n < 2; ++n)
#pragma unroll
            for (int q = 0; q < 4; ++q) {
                int row = brow + wr * 32 + m * 16 + (lane >> 4) * 4 + q;
                int col = bcol + wc * 32 + n * 16 + (lane & 15);
                C[(size_t)row * ldc + col] = acc[m][n][q];
            }
}

// ---------------- split-K fp32 GEMM for indexer projection ----------------
__global__ void gemm_f32_splitk(const float* __restrict__ A, const float* __restrict__ B,
                                float* __restrict__ Cpart, int M, int N, int K) {
    __shared__ float As2[16][64 + 1];
    __shared__ float Bs2[16][64 + 1];
    const int tid = threadIdx.x;
    const int tx = tid & 15, ty = tid >> 4;
    const int brow = blockIdx.y * 64, bcol = blockIdx.x * 64;
    const int z = blockIdx.z;
    const int kbeg = z * KCHUNK, kend = kbeg + KCHUNK;

    float acc[4][4];
#pragma unroll
    for (int i = 0; i < 4; ++i)
#pragma unroll
        for (int j = 0; j < 4; ++j) acc[i][j] = 0.f;

    for (int k0 = kbeg; k0 < kend; k0 += 16) {
#pragma unroll
        for (int it = 0; it < 4; ++it) {
            int i = tid + it * 256;
            int r = i >> 4, c = i & 15;
            As2[c][r] = A[(size_t)(brow + r) * K + (k0 + c)];
        }
#pragma unroll
        for (int it = 0; it < 4; ++it) {
            int i = tid + it * 256;
            int r = i >> 6, c = i & 63;
            int col = bcol + c;
            Bs2[r][c] = (col < N) ? B[(size_t)(k0 + r) * N + col] : 0.f;
        }
        __syncthreads();
#pragma unroll
        for (int kk = 0; kk < 16; ++kk) {
            float a[4], b[4];
#pragma unroll
            for (int i = 0; i < 4; ++i) a[i] = As2[kk][ty * 4 + i];
#pragma unroll
            for (int j = 0; j < 4; ++j) b[j] = Bs2[kk][tx * 4 + j];
#pragma unroll
            for (int i = 0; i < 4; ++i)
#pragma unroll
                for (int j = 0; j < 4; ++j) acc[i][j] += a[i] * b[j];
        }
        __syncthreads();
    }
#pragma unroll
    for (int i = 0; i < 4; ++i) {
        int r = brow + ty * 4 + i;
#pragma unroll
        for (int j = 0; j < 4; ++j) {
            int c = bcol + tx * 4 + j;
            if (c < N) Cpart[((size_t)z * M + r) * N + c] = acc[i][j];
        }
    }
}

// ---------------- reduce split-K partials ----------------
__global__ __launch_bounds__(256) void reduce_k(const float* __restrict__ Cpart,
                                                float* __restrict__ Cout, int MN) {
    int e = blockIdx.x * 256 + threadIdx.x;
    if (e >= MN) return;
    float s = 0.f;
#pragma unroll
    for (int z = 0; z < KSPLIT; ++z) s += Cpart[(size_t)z * MN + e];
    Cout[e] = s;
}

// ---------------- concat indexer weights into Wi_cat [2048][164] f32 ----------------
__global__ __launch_bounds__(256) void copy_wi(const float* __restrict__ Wqi,
                                               const float* __restrict__ Wwi,
                                               const float* __restrict__ Wki,
                                               float* __restrict__ Wi) {
    int e = blockIdx.x * 256 + threadIdx.x;
    if (e >= HID_ * NIDX) return;
    int k = e / NIDX, c = e - k * NIDX;
    float v;
    if (c < 128) v = Wqi[(size_t)k * 128 + c];
    else if (c < 132) v = Wwi[(size_t)k * 4 + (c - 128)];
    else v = Wki[(size_t)k * 32 + (c - 132)];
    Wi[e] = v;
}

// ---------------- RoPE + RMSNorm q (in place in proj, f32) ----------------
__global__ void rope_rms_q(float* __restrict__ proj, const float* __restrict__ cosb,
                           const float* __restrict__ sinb) {
    const int t = blockIdx.x, h = blockIdx.y, lane = threadIdx.x;  // block 64
    float* row = proj + (size_t)t * NPROJ + h * DH;
    float a = row[lane], b = row[lane + 64];
    float c0 = cosb[t * DH + lane],      s0 = sinb[t * DH + lane];
    float c1 = cosb[t * DH + lane + 64], s1 = sinb[t * DH + lane + 64];
    float r0 = a * c0 - b * s0;
    float r1 = b * c1 + a * s1;
    float ss = r0 * r0 + r1 * r1;
#pragma unroll
    for (int o = 32; o > 0; o >>= 1) ss += __shfl_xor(ss, o);
    float inv = rsqrtf(ss * (1.0f / 128.0f) + 1.1920929e-07f);
    row[lane] = r0 * inv;
    row[lane + 64] = r1 * inv;
}

// ---------------- RoPE + RMSNorm k -> bf16 kbb ----------------
__global__ void rope_rms_k(const float* __restrict__ proj, const float* __restrict__ cosb,
                           const float* __restrict__ sinb, unsigned short* __restrict__ kbb) {
    const int t = blockIdx.x, h = blockIdx.y, lane = threadIdx.x;  // block 64
    const float* row = proj + (size_t)t * NPROJ + HID_ + h * DH;
    float a = row[lane], b = row[lane + 64];
    float c0 = cosb[t * DH + lane],      s0 = sinb[t * DH + lane];
    float c1 = cosb[t * DH + lane + 64], s1 = sinb[t * DH + lane + 64];
    float r0 = a * c0 - b * s0;
    float r1 = b * c1 + a * s1;
    float ss = r0 * r0 + r1 * r1;
#pragma unroll
    for (int o = 32; o > 0; o >>= 1) ss += __shfl_xor(ss, o);
    float inv = rsqrtf(ss * (1.0f / 128.0f) + 1.1920929e-07f);
    unsigned short* dst = kbb + ((size_t)t * NKV + h) * DH;
    dst[lane] = (unsigned short)packbf(r0 * inv);
    dst[lane + 64] = (unsigned short)packbf(r1 * inv);
}

// ---------------- cast v -> bf16 (2 elems/thread) ----------------
__global__ __launch_bounds__(256) void cast_v(const float* __restrict__ proj,
                                              unsigned int* __restrict__ vbb) {
    int e = blockIdx.x * 256 + threadIdx.x;       // 1024*256
    int t = e >> 8, c2 = e & 255;
    const float* src = proj + (size_t)t * NPROJ + HID_ + 512 + 2 * c2;
    vbb[(size_t)t * 256 + c2] = packbf(src[0]) | (packbf(src[1]) << 16);
}

// ---------------- tiled lightning indexer: 64x64 (t,s) tiles, fp32 ----------------
__global__ __launch_bounds__(256) void indexer_tiled(const float* __restrict__ proji,
                                                     float* __restrict__ S) {
    const int sb = blockIdx.x, tb = blockIdx.y;
    if (sb > tb) return;
    __shared__ float qs[64][132];
    __shared__ float wsm[64][4];
    __shared__ float ks[64][36];
    const int tid = threadIdx.x;

#pragma unroll
    for (int it = 0; it < 8; ++it) {
        int i = tid + it * 256;
        int r = i >> 5, c4 = i & 31;
        *(float4*)&qs[r][c4 * 4] = *(const float4*)&proji[(size_t)(tb * 64 + r) * NIDX + c4 * 4];
    }
    {
        int r = tid >> 2, j = tid & 3;
        wsm[r][j] = proji[(size_t)(tb * 64 + r) * NIDX + 128 + j];
    }
#pragma unroll
    for (int it = 0; it < 2; ++it) {
        int i = tid + it * 256;
        int r = i >> 3, c4 = i & 7;
        *(float4*)&ks[r][c4 * 4] = *(const float4*)&proji[(size_t)(sb * 64 + r) * NIDX + 132 + c4 * 4];
    }
    __syncthreads();

    const int tx = tid & 15, ty = tid >> 4;
    float out[4][4] = {};
#pragma unroll
    for (int j = 0; j < HI_; ++j) {
        float acc[4][4] = {};
#pragma unroll
        for (int d4 = 0; d4 < 8; ++d4) {
            float4 a[4], b[4];
#pragma unroll
            for (int i = 0; i < 4; ++i) a[i] = *(const float4*)&qs[ty + i * 16][j * 32 + d4 * 4];
#pragma unroll
            for (int jj = 0; jj < 4; ++jj) b[jj] = *(const float4*)&ks[tx + jj * 16][d4 * 4];
#pragma unroll
            for (int i = 0; i < 4; ++i)
#pragma unroll
                for (int jj = 0; jj < 4; ++jj)
                    acc[i][jj] += a[i].x * b[jj].x + a[i].y * b[jj].y +
                                  a[i].z * b[jj].z + a[i].w * b[jj].w;
        }
#pragma unroll
        for (int i = 0; i < 4; ++i) {
            float w = wsm[ty + i * 16][j];
#pragma unroll
            for (int jj = 0; jj < 4; ++jj)
                out[i][jj] += w * fmaxf(acc[i][jj], 0.f);
        }
    }
#pragma unroll
    for (int i = 0; i < 4; ++i) {
        int t = tb * 64 + ty + i * 16;
#pragma unroll
        for (int jj = 0; jj < 4; ++jj) {
            int s = sb * 64 + tx + jj * 16;
            if (s <= t) S[(size_t)t * T_ + s] = out[i][jj];
        }
    }
}

// ---------------- exact top-256 via radix binary descent ----------------
// Set-equivalent to jax.lax.top_k (ties at threshold -> lowest index).
__global__ __launch_bounds__(256) void topk_radix(const float* __restrict__ S,
                                                  int* __restrict__ idxout) {
    const int t = blockIdx.x, tid = threadIdx.x;
    int* orow = idxout + (size_t)t * TOPK_;
    if (t < TOPK_) { orow[tid] = tid; return; }

    const int n = t + 1;
    const float* Srow = S + (size_t)t * T_;
    const int lane = tid & 63, wave = tid >> 6;

    // order-preserving key transform; masked slots -> 0 (never selected)
    unsigned int key[4];
#pragma unroll
    for (int j = 0; j < 4; ++j) {
        int s = j * 256 + tid;
        if (s < n) {
            unsigned int u = __float_as_uint(Srow[s]);
            key[j] = (u & 0x80000000u) ? ~u : (u | 0x80000000u);
        } else key[j] = 0u;
    }

    __shared__ int wcnt[2][4];
    unsigned int prefix = 0;
#pragma unroll 1
    for (int b = 31; b >= 0; --b) {
        unsigned int cand = prefix | (1u << b);
        int c = (key[0] >= cand) + (key[1] >= cand) + (key[2] >= cand) + (key[3] >= cand);
#pragma unroll
        for (int o = 32; o > 0; o >>= 1) c += __shfl_xor(c, o);
        if (lane == 0) wcnt[b & 1][wave] = c;
        __syncthreads();
        int total = wcnt[b & 1][0] + wcnt[b & 1][1] + wcnt[b & 1][2] + wcnt[b & 1][3];
        if (total >= TOPK_) prefix = cand;
    }
    const unsigned int T = prefix;   // 256th-largest key

    // count strictly-greater
    __shared__ int posc;
    __shared__ int eqtot[4][4];
    __syncthreads();
    {
        int c = (key[0] > T) + (key[1] > T) + (key[2] > T) + (key[3] > T);
#pragma unroll
        for (int o = 32; o > 0; o >>= 1) c += __shfl_xor(c, o);
        if (lane == 0) wcnt[0][wave] = c;
    }
    if (tid == 0) posc = 0;

    // ballots for equals (index order = slot-major ascending)
    int e[4]; int myp[4];
    unsigned long long lmask = (lane == 63) ? 0xFFFFFFFFFFFFFFFFull >> 1
                                            : ((1ull << lane) - 1ull);
#pragma unroll
    for (int j = 0; j < 4; ++j) {
        e[j] = (key[j] == T) ? 1 : 0;
        unsigned long long m = __ballot(e[j]);
        myp[j] = __popcll(m & ((1ull << lane) - 1ull));
        if (lane == 0) eqtot[j][wave] = __popcll(m);
    }
    (void)lmask;
    __syncthreads();
    const int cntGT = wcnt[0][0] + wcnt[0][1] + wcnt[0][2] + wcnt[0][3];
    const int need = TOPK_ - cntGT;

    // emit strictly-greater (order-free)
#pragma unroll
    for (int j = 0; j < 4; ++j)
        if (key[j] > T) {
            int p = atomicAdd(&posc, 1);
            orow[p] = j * 256 + tid;
        }
    // emit lowest-index equals
    int runbase = 0;
#pragma unroll
    for (int j = 0; j < 4; ++j) {
        int wavebase = 0;
#pragma unroll
        for (int w2 = 0; w2 < 4; ++w2) if (w2 < wave) wavebase += eqtot[j][w2];
        int g = runbase + wavebase + myp[j];
        if (e[j] && g < need) orow[cntGT + g] = j * 256 + tid;
        runbase += eqtot[j][0] + eqtot[j][1] + eqtot[j][2] + eqtot[j][3];
    }
}

// ---------------- sparse GQA with LDS-staged K/V tiles ----------------
#define KSS 136   // ushort units per staged row (272B = 17*16B)
__global__ __launch_bounds__(256) void attn2(const float* __restrict__ proj,
                                             const unsigned short* __restrict__ kbb,
                                             const unsigned short* __restrict__ vbb,
                                             const int* __restrict__ idx,
                                             unsigned short* __restrict__ attnb) {
    const int t = blockIdx.x, n = blockIdx.y;
    const int tid = threadIdx.x, lane = tid & 63, w = tid >> 6;
    const int C = (t + 1 < TOPK_) ? t + 1 : TOPK_;

    __shared__ float Qs[4][128];
    __shared__ unsigned short Ks[64 * KSS];
    __shared__ float sp[4][TOPK_];
    __shared__ int sidx[TOPK_];

    sidx[tid] = idx[(size_t)t * TOPK_ + tid];
    {
        const float* qbase = proj + (size_t)t * NPROJ + n * 512;
        Qs[tid >> 7][tid & 127] = qbase[tid];
        Qs[(tid + 256) >> 7][tid & 127] = qbase[tid + 256];
    }
    __syncthreads();

    float sc[4];
#pragma unroll 1
    for (int tau = 0; tau < 4; ++tau) {
#pragma unroll
        for (int it = 0; it < 4; ++it) {
            int c = tid + it * 256;
            int r = c >> 4, off = (c & 15) * 8;
            int s = sidx[tau * 64 + r];
            *(uint4*)&Ks[r * KSS + off] = *(const uint4*)&kbb[((size_t)s * NKV + n) * DH + off];
        }
        __syncthreads();
        int j = tau * 64 + lane;
        float acc = 0.f;
        const unsigned short* kr = &Ks[lane * KSS];
#pragma unroll
        for (int d0 = 0; d0 < 16; ++d0) {
            uint4 kv = *(const uint4*)(kr + d0 * 8);
            const float* qp = &Qs[w][d0 * 8];
            float4 q0 = *(const float4*)qp;
            float4 q1 = *(const float4*)(qp + 4);
            acc += bflo(kv.x) * q0.x + bfhi(kv.x) * q0.y
                 + bflo(kv.y) * q0.z + bfhi(kv.y) * q0.w
                 + bflo(kv.z) * q1.x + bfhi(kv.z) * q1.y
                 + bflo(kv.w) * q1.z + bfhi(kv.w) * q1.w;
        }
        sc[tau] = (j < C) ? acc * 0.08838834764831845f : -INFINITY;
        __syncthreads();
    }
    float m = fmaxf(fmaxf(sc[0], sc[1]), fmaxf(sc[2], sc[3]));
#pragma unroll
    for (int o = 32; o > 0; o >>= 1) m = fmaxf(m, __shfl_xor(m, o));
    float sum = 0.f;
#pragma unroll
    for (int tau = 0; tau < 4; ++tau) {
        float e = expf(sc[tau] - m);
        sp[w][tau * 64 + lane] = e;
        sum += e;
    }
#pragma unroll
    for (int o = 32; o > 0; o >>= 1) sum += __shfl_xor(sum, o);
    float inv = 1.f / sum;

    float o0 = 0.f, o1 = 0.f;
#pragma unroll 1
    for (int tau = 0; tau < 4; ++tau) {
#pragma unroll
        for (int it = 0; it < 4; ++it) {
            int c = tid + it * 256;
            int r = c >> 4, off = (c & 15) * 8;
            int s = sidx[tau * 64 + r];
            *(uint4*)&Ks[r * KSS + off] = *(const uint4*)&vbb[((size_t)s * NKV + n) * DH + off];
        }
        __syncthreads();
        const float* pw = &sp[w][tau * 64];
        const unsigned short* vb0 = &Ks[2 * lane];
#pragma unroll
        for (int jj = 0; jj < 64; ++jj) {
            float p = pw[jj];
            unsigned int uv = *(const unsigned int*)(vb0 + jj * KSS);
            o0 += p * bflo(uv);
            o1 += p * bfhi(uv);
        }
        __syncthreads();
    }
    o0 *= inv; o1 *= inv;
    unsigned int res = packbf(o0) | (packbf(o1) << 16);
    *(unsigned int*)&attnb[(size_t)t * HID_ + (n * 4 + w) * DH + 2 * lane] = res;
}

// ---------------- launch ----------------
extern "C" void kernel_launch(void* const* d_in, const int* in_sizes, int n_in,
                              void* d_out, int out_size, void* d_ws, size_t ws_size,
                              hipStream_t stream) {
    const float* x    = (const float*)d_in[0];
    const float* cosb = (const float*)d_in[1];
    const float* sinb = (const float*)d_in[2];
    const float* Wq   = (const float*)d_in[3];
    const float* Wk   = (const float*)d_in[4];
    const float* Wv   = (const float*)d_in[5];
    const float* Wo   = (const float*)d_in[6];
    const float* Wqi  = (const float*)d_in[7];
    const float* Wwi  = (const float*)d_in[8];
    const float* Wki  = (const float*)d_in[9];
    float* out = (float*)d_out;

    unsigned short* xb    = (unsigned short*)d_ws;             // 1024*2048 bf16
    unsigned short* WtAll = xb + 2097152;                      // 3072*2048 bf16
    float*  proj  = (float*)(WtAll + 6291456);                 // 1024*3072 f32
    float*  Wi    = proj + 3145728;                            // 2048*164 f32
    float*  proji = Wi + 335872;                               // 1024*164 f32
    float*  S     = proji + 167936;                            // 1024*1024 f32
    int*    idxb  = (int*)(S + 1048576);                       // 1024*256 int
    unsigned short* kbb   = (unsigned short*)(idxb + 262144);  // 1024*512 bf16
    unsigned short* vbb   = kbb + 524288;                      // 1024*512 bf16
    unsigned short* attnb = vbb + 524288;                      // 1024*2048 bf16
    unsigned short* Wot   = WtAll;                             // reuse after proj GEMM
    float* Cpart = (float*)kbb;   // split-K partials, dead before kbb written

    // casts / transposes
    cast_x<<<dim3(1024), dim3(256), 0, stream>>>(x, xb, 262144);
    tcast<<<dim3(64, 64), dim3(32, 8), 0, stream>>>(Wq, WtAll, HID_);
    tcast<<<dim3(16, 64), dim3(32, 8), 0, stream>>>(Wk, WtAll + (size_t)2048 * HID_, 512);
    tcast<<<dim3(16, 64), dim3(32, 8), 0, stream>>>(Wv, WtAll + (size_t)2560 * HID_, 512);
    copy_wi<<<dim3((HID_ * NIDX + 255) / 256), dim3(256), 0, stream>>>(Wqi, Wwi, Wki, Wi);

    // projections
    gemm_bf16t<<<dim3(NPROJ / 64, T_ / 64), dim3(256), 0, stream>>>(xb, WtAll, proj, HID_, NPROJ);
    gemm_f32_splitk<<<dim3((NIDX + 63) / 64, T_ / 64, KSPLIT), dim3(256), 0, stream>>>(x, Wi, Cpart, T_, NIDX, HID_);
    reduce_k<<<dim3((T_ * NIDX + 255) / 256), dim3(256), 0, stream>>>(Cpart, proji, T_ * NIDX);

    // Wo transpose can reuse WtAll space now
    tcast<<<dim3(64, 64), dim3(32, 8), 0, stream>>>(Wo, Wot, HID_);

    // rope + rms, v cast (kbb/vbb written only after Cpart is dead)
    rope_rms_q<<<dim3(T_, NH), dim3(64), 0, stream>>>(proj, cosb, sinb);
    rope_rms_k<<<dim3(T_, NKV), dim3(64), 0, stream>>>(proj, cosb, sinb, kbb);
    cast_v<<<dim3(1024), dim3(256), 0, stream>>>(proj, (unsigned int*)vbb);

    // indexer scores + topk
    indexer_tiled<<<dim3(16, 16), dim3(256), 0, stream>>>(proji, S);
    topk_radix<<<dim3(T_), dim3(256), 0, stream>>>(S, idxb);

    // sparse attention
    attn2<<<dim3(T_, NKV), dim3(256), 0, stream>>>(proj, kbb, vbb, idxb, attnb);

    // output projection
    gemm_bf16t<<<dim3(HID_ / 64, T_ / 64), dim3(256), 0, stream>>>(attnb, Wot, out, HID_, HID_);
}